// Round 11
// baseline (193.757 us; speedup 1.0000x reference)
//
#include <hip/hip_runtime.h>
#include <hip/hip_bf16.h>
#include <math.h>

typedef __hip_bfloat16 bf16;
typedef __attribute__((ext_vector_type(8))) short bf16x8;
typedef __attribute__((ext_vector_type(4))) float f32x4;

__device__ __forceinline__ short f2bf_s(float v){ union{ bf16 b; short s;} u; u.b = __float2bfloat16(v); return u.s; }

// async global->LDS 16B (m97 pattern: lds dest = wave-uniform base + lane*16)
__device__ __forceinline__ void gl_lds16(const bf16* g, short* l) {
    __builtin_amdgcn_global_load_lds(
        (const __attribute__((address_space(1))) void*)g,
        (__attribute__((address_space(3))) void*)l, 16, 0, 0);
}

#define LN2F 0.69314718055994531f

__device__ __forceinline__ void cvt_store4(bf16* d, size_t idx, float4 v) {
    union { ushort4 u; bf16 b[4]; } o;
    o.b[0] = __float2bfloat16(v.x);
    o.b[1] = __float2bfloat16(v.y);
    o.b[2] = __float2bfloat16(v.z);
    o.b[3] = __float2bfloat16(v.w);
    ((ushort4*)d)[idx] = o.u;
}

// ---------- single merged conversion kernel ----------
__global__ __launch_bounds__(256)
void conv_all(const float* __restrict__ query, const float* __restrict__ pquery,
              const float* __restrict__ Wpq, const float* __restrict__ Wpc,
              const float* __restrict__ Wq, const float* __restrict__ Wc,
              const float* __restrict__ Wo,
              const float* __restrict__ bpc, const float* __restrict__ bq,
              const float* __restrict__ bc,
              bf16* __restrict__ qbf, bf16* __restrict__ pqy, bf16* __restrict__ wpq,
              bf16* __restrict__ wcat, bf16* __restrict__ wo_bf,
              float* __restrict__ biascat)
{
    int blk = blockIdx.x;
    if (blk < 4096) {
        int i = blk * 256 + threadIdx.x;
        cvt_store4(qbf, i, ((const float4*)query)[i]);
    } else if (blk < 4160) {
        int i = (blk - 4096) * 256 + threadIdx.x;
        cvt_store4(pqy, i, ((const float4*)pquery)[i]);
    } else if (blk < 5184) {
        int i = (blk - 4160) * 256 + threadIdx.x;
        cvt_store4(wpq, i, ((const float4*)Wpq)[i]);
    } else if (blk < 8256) {
        int rel = blk - 5184;
        const float* s = (rel < 1024) ? Wpc : ((rel < 2048) ? Wq : Wc);
        int i = (rel & 1023) * 256 + threadIdx.x;
        cvt_store4(wcat + (size_t)(rel >> 10) * 1048576, i, ((const float4*)s)[i]);
    } else if (blk < 9280) {
        int i = (blk - 8256) * 256 + threadIdx.x;
        cvt_store4(wo_bf, i, ((const float4*)Wo)[i]);
    } else {
        int i = (blk - 9280) * 256 + threadIdx.x;
        if (i < 3072) {
            float v = (i < 1024) ? bpc[i] : ((i < 2048) ? bq[i - 1024] : bc[i - 2048]);
            biascat[i] = v;
        }
    }
}

// ---------- fused projection GEMM (BK=64, dual-slab LDS) + merged pq partials ----------
// Main path (by<32): C[4096][3072] = kp|q|kv, bf16 out.
// pq path (by>=32): part[kslice][64][1024] partials for the pq projection.
__global__ __launch_bounds__(256)
void gemm_fused(const bf16* __restrict__ A, const bf16* __restrict__ B,
                const float* __restrict__ bias, bf16* __restrict__ C,
                int M, int N, int K, float scale_all, float scale_mid,
                const bf16* __restrict__ pqA, const bf16* __restrict__ pqB,
                float* __restrict__ part)
{
    __shared__ short As[8192];   // [2][128][32] slabs
    __shared__ short Bs[8192];

    const int tid  = threadIdx.x;
    const int lane = tid & 63;
    const int wave = tid >> 6;
    const int kb = lane >> 4;
    const int rr = lane & 15;

    if (blockIdx.y < 32) {
        const int m0 = blockIdx.y * 128;
        const int n0 = blockIdx.x * 128;
        const int wm = (wave >> 1) * 64;
        const int wn = (wave & 1) * 64;

        f32x4 acc[4][4] = {};

        for (int k0 = 0; k0 < K; k0 += 64) {
            __syncthreads();
            #pragma unroll
            for (int l = 0; l < 4; ++l) {
                int cc = tid + l * 256;
                int row = (cc >> 2) & 127;
                int slab = cc >> 9;
                int ks8 = cc & 3;
                gl_lds16(A + (size_t)(m0 + row) * K + k0 + slab * 32 + ks8 * 8, As + cc * 8);
                gl_lds16(B + (size_t)(n0 + row) * K + k0 + slab * 32 + ks8 * 8, Bs + cc * 8);
            }
            __syncthreads();

            #pragma unroll
            for (int ks = 0; ks < 2; ++ks) {
                bf16x8 af[4], bfr[4];
                #pragma unroll
                for (int mi = 0; mi < 4; ++mi)
                    af[mi] = *(const bf16x8*)(As + ks * 4096 + (wm + mi * 16 + rr) * 32 + kb * 8);
                #pragma unroll
                for (int ni = 0; ni < 4; ++ni)
                    bfr[ni] = *(const bf16x8*)(Bs + ks * 4096 + (wn + ni * 16 + rr) * 32 + kb * 8);
                #pragma unroll
                for (int mi = 0; mi < 4; ++mi)
                    #pragma unroll
                    for (int ni = 0; ni < 4; ++ni)
                        acc[mi][ni] = __builtin_amdgcn_mfma_f32_16x16x32_bf16(
                            af[mi], bfr[ni], acc[mi][ni], 0, 0, 0);
            }
        }

        const int col_l = lane & 15;
        const int row_q = lane >> 4;
        #pragma unroll
        for (int ni = 0; ni < 4; ++ni) {
            int col = n0 + wn + ni * 16 + col_l;
            float bb = bias[col];
            float sc = ((col >> 10) == 1) ? scale_mid : scale_all;
            #pragma unroll
            for (int mi = 0; mi < 4; ++mi) {
                #pragma unroll
                for (int r = 0; r < 4; ++r) {
                    int row = m0 + wm + mi * 16 + row_q * 4 + r;
                    C[(size_t)row * N + col] = __float2bfloat16(sc * (acc[mi][ni][r] + bb));
                }
            }
        }
    } else {
        // pq partial path (old gemm_pq_partial body, 32-k steps)
        int pqIdx = (blockIdx.y - 32) * 24 + blockIdx.x;
        if (pqIdx >= 64) return;
        const int n0 = (pqIdx & 7) * 128;
        const int kslice = pqIdx >> 3;
        const int kbase = kslice * 128;

        f32x4 acc[4][2] = {};

        const int ra = tid >> 2, sa = tid & 3;
        const int c0 = tid, c1 = tid + 256;
        const int rb0 = c0 >> 2, sb0 = c0 & 3;
        const int rb1 = c1 >> 2, sb1 = c1 & 3;

        for (int k0 = kbase; k0 < kbase + 128; k0 += 32) {
            __syncthreads();
            gl_lds16(pqA + (size_t)ra * 1024 + k0 + sa * 8, As + tid * 8);
            gl_lds16(pqB + (size_t)(n0 + rb0) * 1024 + k0 + sb0 * 8, Bs + c0 * 8);
            gl_lds16(pqB + (size_t)(n0 + rb1) * 1024 + k0 + sb1 * 8, Bs + c1 * 8);
            __syncthreads();

            bf16x8 af[4], bfr[2];
            #pragma unroll
            for (int mi = 0; mi < 4; ++mi)
                af[mi] = *(const bf16x8*)(As + (mi * 16 + rr) * 32 + kb * 8);
            #pragma unroll
            for (int ni = 0; ni < 2; ++ni)
                bfr[ni] = *(const bf16x8*)(Bs + (wave * 32 + ni * 16 + rr) * 32 + kb * 8);
            #pragma unroll
            for (int mi = 0; mi < 4; ++mi)
                #pragma unroll
                for (int ni = 0; ni < 2; ++ni)
                    acc[mi][ni] = __builtin_amdgcn_mfma_f32_16x16x32_bf16(
                        af[mi], bfr[ni], acc[mi][ni], 0, 0, 0);
        }

        const int col_l = lane & 15;
        const int row_q = lane >> 4;
        float* dst = part + (size_t)kslice * 65536;
        #pragma unroll
        for (int ni = 0; ni < 2; ++ni) {
            int col = n0 + wave * 32 + ni * 16 + col_l;
            #pragma unroll
            for (int mi = 0; mi < 4; ++mi) {
                #pragma unroll
                for (int r = 0; r < 4; ++r) {
                    int row = mi * 16 + row_q * 4 + r;
                    dst[(size_t)row * 1024 + col] = acc[mi][ni][r];
                }
            }
        }
    }
}

// ---------- out-projection GEMM: 64x128 tiles, BK=64 dual-slab ----------
__global__ __launch_bounds__(256)
void gemm_bf16_nt64(const bf16* __restrict__ A, const bf16* __restrict__ B,
                    const float* __restrict__ bias, float* __restrict__ C,
                    int M, int N, int K)
{
    __shared__ short As[4096];   // [2][64][32]
    __shared__ short Bs[8192];   // [2][128][32]

    const int tid  = threadIdx.x;
    const int lane = tid & 63;
    const int wave = tid >> 6;
    const int m0 = blockIdx.y * 64;
    const int n0 = blockIdx.x * 128;
    const int wm = (wave >> 1) * 32;
    const int wn = (wave & 1) * 64;

    f32x4 acc[2][4] = {};

    const int kb = lane >> 4;
    const int rr = lane & 15;

    for (int k0 = 0; k0 < K; k0 += 64) {
        __syncthreads();
        #pragma unroll
        for (int l = 0; l < 2; ++l) {
            int cc = tid + l * 256;
            int row = (cc >> 2) & 63;
            int slab = cc >> 8;
            int ks8 = cc & 3;
            gl_lds16(A + (size_t)(m0 + row) * K + k0 + slab * 32 + ks8 * 8, As + cc * 8);
        }
        #pragma unroll
        for (int l = 0; l < 4; ++l) {
            int cc = tid + l * 256;
            int row = (cc >> 2) & 127;
            int slab = cc >> 9;
            int ks8 = cc & 3;
            gl_lds16(B + (size_t)(n0 + row) * K + k0 + slab * 32 + ks8 * 8, Bs + cc * 8);
        }
        __syncthreads();

        #pragma unroll
        for (int ks = 0; ks < 2; ++ks) {
            bf16x8 af[2], bfr[4];
            #pragma unroll
            for (int mi = 0; mi < 2; ++mi)
                af[mi] = *(const bf16x8*)(As + ks * 2048 + (wm + mi * 16 + rr) * 32 + kb * 8);
            #pragma unroll
            for (int ni = 0; ni < 4; ++ni)
                bfr[ni] = *(const bf16x8*)(Bs + ks * 4096 + (wn + ni * 16 + rr) * 32 + kb * 8);
            #pragma unroll
            for (int mi = 0; mi < 2; ++mi)
                #pragma unroll
                for (int ni = 0; ni < 4; ++ni)
                    acc[mi][ni] = __builtin_amdgcn_mfma_f32_16x16x32_bf16(
                        af[mi], bfr[ni], acc[mi][ni], 0, 0, 0);
        }
    }

    const int col_l = lane & 15;
    const int row_q = lane >> 4;
    #pragma unroll
    for (int ni = 0; ni < 4; ++ni) {
        int col = n0 + wn + ni * 16 + col_l;
        float bb = bias[col];
        #pragma unroll
        for (int mi = 0; mi < 2; ++mi) {
            #pragma unroll
            for (int r = 0; r < 4; ++r) {
                int row = m0 + wm + mi * 16 + row_q * 4 + r;
                C[(size_t)row * N + col] = acc[mi][ni][r] + bb;
            }
        }
    }
}

// pq (bf16 out) = 0.125*(sum_s part + bias)
__global__ __launch_bounds__(256)
void pq_reduce(const float* __restrict__ part, const float* __restrict__ bias,
               bf16* __restrict__ pq)
{
    int gid = blockIdx.x * 256 + threadIdx.x;
    int n = gid & 1023;
    float s = bias[n];
    #pragma unroll
    for (int k = 0; k < 8; ++k) s += part[(size_t)k * 65536 + gid];
    pq[gid] = __float2bfloat16(0.125f * s);
}

// ---------- MFMA pattn + chunk-local state sum ----------
__global__ __launch_bounds__(256)
void pattn_sum_kernel(const bf16* __restrict__ kp, const bf16* __restrict__ kv,
                      const bf16* __restrict__ pqb, bf16* __restrict__ pattn,
                      float* __restrict__ Sbuf, int T, int ld)
{
    __shared__ short sKP[64 * 72];
    __shared__ short sKVT[64 * 72];
    __shared__ short sPQ[32 * 72];
    __shared__ short sPT[32 * 72];

    const int c = blockIdx.x, bh = blockIdx.y;
    const int b = bh >> 4, h = bh & 15;
    const int t0 = c * 64;
    const int tid = threadIdx.x;
    const int lane = tid & 63, wave = tid >> 6;
    const int rr = lane & 15, kb = lane >> 4;
    const int m0w = wave * 16;

    #pragma unroll
    for (int l = 0; l < 2; ++l) {
        int idx = tid + l * 256;
        int t = idx >> 3, d8 = (idx & 7) * 8;
        size_t g = (size_t)((t0 + t) * 2 + b) * ld + h * 64 + d8;
        uint4 vk = *(const uint4*)(kp + g);
        *(uint4*)(sKP + t * 72 + d8) = vk;
        uint4 vv = *(const uint4*)(kv + g + 2048);
        union { uint4 u; short s[8]; } cw; cw.u = vv;
        #pragma unroll
        for (int i = 0; i < 8; ++i) sKVT[(d8 + i) * 72 + t] = cw.s[i];
    }
    {
        int p = tid >> 3, d8 = (tid & 7) * 8;
        uint4 v = *(const uint4*)(pqb + (size_t)(p * 2 + b) * 1024 + h * 64 + d8);
        *(uint4*)(sPQ + p * 72 + d8) = v;
    }
    __syncthreads();

    // pattn: C[t][p] = softplus(ln2 * kp.pq)/ln2
    {
        bf16x8 a0 = *(const bf16x8*)(sKP + (m0w + rr) * 72 + kb * 8);
        bf16x8 a1 = *(const bf16x8*)(sKP + (m0w + rr) * 72 + 32 + kb * 8);
        f32x4 acc[2] = {};
        #pragma unroll
        for (int nt = 0; nt < 2; ++nt) {
            bf16x8 b0 = *(const bf16x8*)(sPQ + (nt * 16 + rr) * 72 + kb * 8);
            bf16x8 b1 = *(const bf16x8*)(sPQ + (nt * 16 + rr) * 72 + 32 + kb * 8);
            acc[nt] = __builtin_amdgcn_mfma_f32_16x16x32_bf16(a0, b0, acc[nt], 0, 0, 0);
            acc[nt] = __builtin_amdgcn_mfma_f32_16x16x32_bf16(a1, b1, acc[nt], 0, 0, 0);
        }
        #pragma unroll
        for (int nt = 0; nt < 2; ++nt)
            #pragma unroll
            for (int r = 0; r < 4; ++r) {
                int t = m0w + kb * 4 + r;
                int p = nt * 16 + rr;
                float z = LN2F * acc[nt][r];
                float sp = (fmaxf(z, 0.f) + log1pf(__expf(-fabsf(z)))) / LN2F;
                short sb = f2bf_s(sp);
                sPT[p * 72 + t] = sb;
                ((unsigned short*)pattn)[((size_t)bh * T + t0 + t) * 32 + p] = (unsigned short)sb;
            }
    }
    __syncthreads();

    // S[i][j] = sum_t kv[t][i]*p[t][j]
    {
        bf16x8 a0 = *(const bf16x8*)(sKVT + (m0w + rr) * 72 + kb * 8);
        bf16x8 a1 = *(const bf16x8*)(sKVT + (m0w + rr) * 72 + 32 + kb * 8);
        f32x4 acc[2] = {};
        #pragma unroll
        for (int nt = 0; nt < 2; ++nt) {
            bf16x8 b0 = *(const bf16x8*)(sPT + (nt * 16 + rr) * 72 + kb * 8);
            bf16x8 b1 = *(const bf16x8*)(sPT + (nt * 16 + rr) * 72 + 32 + kb * 8);
            acc[nt] = __builtin_amdgcn_mfma_f32_16x16x32_bf16(a0, b0, acc[nt], 0, 0, 0);
            acc[nt] = __builtin_amdgcn_mfma_f32_16x16x32_bf16(a1, b1, acc[nt], 0, 0, 0);
        }
        float* Sdst = Sbuf + ((size_t)bh * 32 + c) * 2048;
        #pragma unroll
        for (int nt = 0; nt < 2; ++nt)
            #pragma unroll
            for (int r = 0; r < 4; ++r) {
                int i = m0w + kb * 4 + r;
                int j = nt * 16 + rr;
                Sdst[i * 32 + j] = acc[nt][r];
            }
    }
}

// In-place exclusive prefix over chunks
__global__ __launch_bounds__(256)
void prefix_state_kernel(float* __restrict__ Sbuf)
{
    const int NCH = 32;
    int gid = blockIdx.x * 256 + threadIdx.x;
    int bh = gid >> 11, e = gid & 2047;
    float* p = Sbuf + (size_t)bh * NCH * 2048 + e;
    float run = 0.f;
    #pragma unroll
    for (int c = 0; c < NCH; ++c) {
        float t = p[c * 2048];
        p[c * 2048] = run;
        run += t;
    }
}

// ---------- MFMA chunk_attn (bf16 inputs), 52224 B LDS -> 3 blocks/CU ----------
__global__ __launch_bounds__(256)
void chunk_attn(const bf16* __restrict__ qg, const bf16* __restrict__ kvg,
                const bf16* __restrict__ pg, const float* __restrict__ Sg,
                bf16* __restrict__ attn, int T, int ld)
{
    __shared__ short sm[26112];
    short* sQ   = sm;          // overlaid by sKVT after stage 3
    short* sKV  = sm + 4608;
    short* sW   = sm + 9216;
    short* sAW  = sm + 13824;
    short* sS   = sm + 16384;
    short* sST  = sm + 18944;
    short* sP   = sm + 21248;
    short* sPT  = sm + 23808;

    const int bh = blockIdx.y, c = blockIdx.x;
    const int b = bh >> 4, h = bh & 15;
    const int t0 = c * 64;
    const int tid = threadIdx.x;
    const int lane = tid & 63;
    const int wave = tid >> 6;
    const int rr = lane & 15;
    const int kb = lane >> 4;
    const int m0w = wave * 16;
    const float* Sblk = Sg + ((size_t)bh * 32 + c) * 2048;

    // ---- staging ----
    #pragma unroll
    for (int l = 0; l < 2; ++l) {
        int idx = tid + l * 256;
        int t = idx >> 3, d8 = (idx & 7) * 8;
        size_t g = (size_t)((t0 + t) * 2 + b) * ld + h * 64 + d8;
        uint4 qv = *(const uint4*)(qg + g);
        *(uint4*)(sQ + t * 72 + d8) = qv;
        uint4 kvv = *(const uint4*)(kvg + g);
        *(uint4*)(sKV + t * 72 + d8) = kvv;
    }
    {
        int t = tid >> 2, j8 = (tid & 3) * 8;
        uint4 pv = *(const uint4*)(pg + ((size_t)bh * T + t0 + t) * 32 + j8);
        *(uint4*)(sP + t * 40 + j8) = pv;
        union { uint4 u; short s[8]; } cp; cp.u = pv;
        #pragma unroll
        for (int i = 0; i < 8; ++i) sPT[(j8 + i) * 72 + t] = cp.s[i];

        float4 s0 = *(const float4*)(Sblk + t * 32 + j8);
        float4 s1 = *(const float4*)(Sblk + t * 32 + j8 + 4);
        union { ushort4 u; short s[4]; bf16 bb[4]; } c0, c1;
        c0.bb[0] = __float2bfloat16(s0.x);
        c0.bb[1] = __float2bfloat16(s0.y);
        c0.bb[2] = __float2bfloat16(s0.z);
        c0.bb[3] = __float2bfloat16(s0.w);
        c1.bb[0] = __float2bfloat16(s1.x);
        c1.bb[1] = __float2bfloat16(s1.y);
        c1.bb[2] = __float2bfloat16(s1.z);
        c1.bb[3] = __float2bfloat16(s1.w);
        *(ushort4*)(sS + t * 40 + j8) = c0.u;
        *(ushort4*)(sS + t * 40 + j8 + 4) = c1.u;
        #pragma unroll
        for (int i = 0; i < 4; ++i) sST[(j8 + i) * 72 + t] = c0.s[i];
        #pragma unroll
        for (int i = 0; i < 4; ++i) sST[(j8 + 4 + i) * 72 + t] = c1.s[i];
    }
    __syncthreads();

    // ---- stage 2: QKm = causal(Q · KV^T) -> sW bf16 ----
    {
        bf16x8 aq0 = *(const bf16x8*)(sQ + (m0w + rr) * 72 + kb * 8);
        bf16x8 aq1 = *(const bf16x8*)(sQ + (m0w + rr) * 72 + 32 + kb * 8);
        f32x4 acc[4] = {};
        #pragma unroll
        for (int nt = 0; nt < 4; ++nt) {
            bf16x8 b0 = *(const bf16x8*)(sKV + (nt * 16 + rr) * 72 + kb * 8);
            bf16x8 b1 = *(const bf16x8*)(sKV + (nt * 16 + rr) * 72 + 32 + kb * 8);
            acc[nt] = __builtin_amdgcn_mfma_f32_16x16x32_bf16(aq0, b0, acc[nt], 0, 0, 0);
            acc[nt] = __builtin_amdgcn_mfma_f32_16x16x32_bf16(aq1, b1, acc[nt], 0, 0, 0);
        }
        #pragma unroll
        for (int nt = 0; nt < 4; ++nt)
            #pragma unroll
            for (int r = 0; r < 4; ++r) {
                int t = m0w + kb * 4 + r;
                int s = nt * 16 + rr;
                sW[t * 72 + s] = f2bf_s((s <= t) ? acc[nt][r] : 0.f);
            }
    }
    __syncthreads();

    // ---- stage 3: AW = (Q·S + QKm·P)/len, softmax(32) -> sAW bf16 ----
    {
        bf16x8 aq0 = *(const bf16x8*)(sQ + (m0w + rr) * 72 + kb * 8);
        bf16x8 aq1 = *(const bf16x8*)(sQ + (m0w + rr) * 72 + 32 + kb * 8);
        bf16x8 aw0 = *(const bf16x8*)(sW + (m0w + rr) * 72 + kb * 8);
        bf16x8 aw1 = *(const bf16x8*)(sW + (m0w + rr) * 72 + 32 + kb * 8);
        f32x4 acc[2] = {};
        #pragma unroll
        for (int nt = 0; nt < 2; ++nt) {
            bf16x8 bs0 = *(const bf16x8*)(sST + (nt * 16 + rr) * 72 + kb * 8);
            bf16x8 bs1 = *(const bf16x8*)(sST + (nt * 16 + rr) * 72 + 32 + kb * 8);
            bf16x8 bp0 = *(const bf16x8*)(sPT + (nt * 16 + rr) * 72 + kb * 8);
            bf16x8 bp1 = *(const bf16x8*)(sPT + (nt * 16 + rr) * 72 + 32 + kb * 8);
            acc[nt] = __builtin_amdgcn_mfma_f32_16x16x32_bf16(aq0, bs0, acc[nt], 0, 0, 0);
            acc[nt] = __builtin_amdgcn_mfma_f32_16x16x32_bf16(aq1, bs1, acc[nt], 0, 0, 0);
            acc[nt] = __builtin_amdgcn_mfma_f32_16x16x32_bf16(aw0, bp0, acc[nt], 0, 0, 0);
            acc[nt] = __builtin_amdgcn_mfma_f32_16x16x32_bf16(aw1, bp1, acc[nt], 0, 0, 0);
        }
        #pragma unroll
        for (int r = 0; r < 4; ++r) {
            int t = m0w + kb * 4 + r;
            float inv_len = 1.0f / (float)(t0 + t + 1);
            float v0 = acc[0][r] * inv_len;
            float v1 = acc[1][r] * inv_len;
            float m = fmaxf(v0, v1);
            m = fmaxf(m, __shfl_xor(m, 1));
            m = fmaxf(m, __shfl_xor(m, 2));
            m = fmaxf(m, __shfl_xor(m, 4));
            m = fmaxf(m, __shfl_xor(m, 8));
            float e0 = __expf(v0 - m), e1 = __expf(v1 - m);
            float s = e0 + e1;
            s += __shfl_xor(s, 1);
            s += __shfl_xor(s, 2);
            s += __shfl_xor(s, 4);
            s += __shfl_xor(s, 8);
            float rs = 1.0f / s;
            sAW[t * 40 + rr]      = f2bf_s(e0 * rs);
            sAW[t * 40 + 16 + rr] = f2bf_s(e1 * rs);
        }
    }
    __syncthreads();   // sQ now dead; sAW visible

    // ---- stage 4: transpose KV into dead sQ arena + AP = causal(AW · P^T) ----
    short* sKVT = sQ;
    {
        #pragma unroll
        for (int l = 0; l < 2; ++l) {
            int idx = tid + l * 256;
            int t = idx >> 3, d8 = (idx & 7) * 8;
            union { uint4 u; short s[8]; } ck;
            ck.u = *(const uint4*)(sKV + t * 72 + d8);
            #pragma unroll
            for (int i = 0; i < 8; ++i) sKVT[(d8 + i) * 72 + t] = ck.s[i];
        }
        bf16x8 aa = *(const bf16x8*)(sAW + (m0w + rr) * 40 + kb * 8);
        f32x4 acc[4] = {};
        #pragma unroll
        for (int nt = 0; nt < 4; ++nt) {
            bf16x8 bp = *(const bf16x8*)(sP + (nt * 16 + rr) * 40 + kb * 8);
            acc[nt] = __builtin_amdgcn_mfma_f32_16x16x32_bf16(aa, bp, acc[nt], 0, 0, 0);
        }
        __syncthreads();
        #pragma unroll
        for (int nt = 0; nt < 4; ++nt)
            #pragma unroll
            for (int r = 0; r < 4; ++r) {
                int t = m0w + kb * 4 + r;
                int s = nt * 16 + rr;
                sW[t * 72 + s] = f2bf_s((s <= t) ? acc[nt][r] : 0.f);
            }
    }
    __syncthreads();

    // ---- stage 5: OUT = (AW·S^T + AP·KV)/len -> bf16 global ----
    {
        bf16x8 aa  = *(const bf16x8*)(sAW + (m0w + rr) * 40 + kb * 8);
        bf16x8 ap0 = *(const bf16x8*)(sW + (m0w + rr) * 72 + kb * 8);
        bf16x8 ap1 = *(const bf16x8*)(sW + (m0w + rr) * 72 + 32 + kb * 8);
        f32x4 acc[4] = {};
        #pragma unroll
        for (int nt = 0; nt < 4; ++nt) {
            bf16x8 bs = *(const bf16x8*)(sS + (nt * 16 + rr) * 40 + kb * 8);
            bf16x8 bk0 = *(const bf16x8*)(sKVT + (nt * 16 + rr) * 72 + kb * 8);
            bf16x8 bk1 = *(const bf16x8*)(sKVT + (nt * 16 + rr) * 72 + 32 + kb * 8);
            acc[nt] = __builtin_amdgcn_mfma_f32_16x16x32_bf16(aa,  bs,  acc[nt], 0, 0, 0);
            acc[nt] = __builtin_amdgcn_mfma_f32_16x16x32_bf16(ap0, bk0, acc[nt], 0, 0, 0);
            acc[nt] = __builtin_amdgcn_mfma_f32_16x16x32_bf16(ap1, bk1, acc[nt], 0, 0, 0);
        }
        #pragma unroll
        for (int nt = 0; nt < 4; ++nt)
            #pragma unroll
            for (int r = 0; r < 4; ++r) {
                int t = m0w + kb * 4 + r;
                int d = nt * 16 + rr;
                float v = acc[nt][r] / (float)(t0 + t + 1);
                ((unsigned short*)attn)[((size_t)((t0 + t) * 2 + b)) * 1024 + h * 64 + d] =
                    (unsigned short)f2bf_s(v);
            }
    }
}

extern "C" void kernel_launch(void* const* d_in, const int* in_sizes, int n_in,
                              void* d_out, int out_size, void* d_ws, size_t ws_size,
                              hipStream_t stream) {
    const float* query  = (const float*)d_in[0];
    const float* pquery = (const float*)d_in[1];
    const float* Wpq = (const float*)d_in[2];
    const float* bpq = (const float*)d_in[3];
    const float* Wq  = (const float*)d_in[4];
    const float* bq  = (const float*)d_in[5];
    const float* Wpc = (const float*)d_in[6];
    const float* bpc = (const float*)d_in[7];
    const float* Wc  = (const float*)d_in[8];
    const float* bc  = (const float*)d_in[9];
    const float* Wo  = (const float*)d_in[10];
    const float* bo  = (const float*)d_in[11];
    float* out = (float*)d_out;

    const int T = 2048, E = 1024, MROWS = 4096;
    const int NCH = 32;

    // workspace layout (floats)
    float* ws = (float*)d_ws;
    float* pq_f      = ws;                         // pq bf16 (64x1024)
    float* Cbig_f    = pq_f + 65536;               // Cbig bf16 (4096x3072)
    float* pattn_f   = Cbig_f + 6291456;           // pattn bf16
    float* S_buf     = pattn_f + 1048576;          // fp32 states
    float* qbf_f     = S_buf + 2097152;            // qbf bf16 (4096x1024)
    float* wcat_f    = qbf_f + 2097152;            // wcat bf16 (3072x1024)
    float* wo_f      = wcat_f + 1572864;           // wo bf16
    float* wpq_f     = wo_f + 524288;              // wpq bf16

    bf16* pq_bf   = (bf16*)pq_f;
    bf16* Cbig    = (bf16*)Cbig_f;
    bf16* pattn_bf= (bf16*)pattn_f;
    bf16* qbf     = (bf16*)qbf_f;
    bf16* wcat    = (bf16*)wcat_f;
    bf16* wo_bf   = (bf16*)wo_f;
    bf16* wpq_bf  = (bf16*)wpq_f;
    bf16* pqy_bf  = (bf16*)pattn_f;                // overlay, consumed before pattn written
    float* biascat = pattn_f + 32768;              // overlay, consumed by GEMM before pattn written
    float* pq_part = S_buf;                        // overlay, consumed before pattn_sum writes S
    bf16* attn_bf = qbf;                           // overlay qbf after fused GEMM

    // 1. all conversions in one kernel
    conv_all<<<9292, 256, 0, stream>>>(query, pquery, Wpq, Wpc, Wq, Wc, Wo,
                                       bpc, bq, bc, qbf, pqy_bf, wpq_bf,
                                       wcat, wo_bf, biascat);
    // 2. fused projection GEMM (BK=64) + pq partials merged
    gemm_fused<<<dim3(24, 35), 256, 0, stream>>>(
        qbf, wcat, biascat, Cbig, MROWS, 3072, E, 1.0f, 0.125f,
        pqy_bf, wpq_bf, pq_part);
    // 3. pq reduce
    pq_reduce<<<256, 256, 0, stream>>>(pq_part, bpq, pq_bf);
    // 4. MFMA pattn + chunk sums
    pattn_sum_kernel<<<dim3(NCH, 32), 256, 0, stream>>>(
        Cbig, Cbig, pq_bf, pattn_bf, S_buf, T, 3072);
    // 5. exclusive prefix
    prefix_state_kernel<<<256, 256, 0, stream>>>(S_buf);
    // 6. attention
    chunk_attn<<<dim3(NCH, 32), 256, 0, stream>>>(
        Cbig + 1024, Cbig + 2048, pattn_bf, S_buf, attn_bf, T, 3072);
    // 7. output projection (64x128 tiles, BK=64)
    gemm_bf16_nt64<<<dim3(8, 64), 256, 0, stream>>>(
        attn_bf, wo_bf, bo, out, MROWS, E, E);
}